// Round 7
// baseline (429.082 us; speedup 1.0000x reference)
//
#include <hip/hip_runtime.h>
#include <stdint.h>
#include <stddef.h>

// ---------- types ----------
typedef _Float16 f16_t;
typedef _Float16 f16x8 __attribute__((ext_vector_type(8)));
typedef _Float16 f16x4 __attribute__((ext_vector_type(4)));
typedef float    f32x4 __attribute__((ext_vector_type(4)));

#define AS_G __attribute__((address_space(1)))
#define AS_L __attribute__((address_space(3)))

__device__ __forceinline__ void gload_lds16(const void* g, void* l) {
  // async global->LDS, 16B per lane; HW writes lds_base + lane*16
  __builtin_amdgcn_global_load_lds((const AS_G uint32_t*)g, (AS_L uint32_t*)l, 16, 0, 0);
}

// stage 32 rows x 64 f16 (4 calls of 8 rows) for one wave
__device__ __forceinline__ void stage8(const f16_t* g, int ld, char* l) {
#pragma unroll
  for (int j = 0; j < 4; ++j)
    gload_lds16(g + (size_t)(j * 8) * ld, l + j * 1024);
}

#define LN_EPS 1e-12f

// ---------- cast fp32 -> f16 (vectorized x4) ----------
__global__ __launch_bounds__(256) void cast_f16_kernel(const float* __restrict__ in,
                                                       f16_t* __restrict__ out) {
  int i = blockIdx.x * 256 + threadIdx.x;
  float4 v = ((const float4*)in)[i];
  f16x4 o = {(f16_t)v.x, (f16_t)v.y, (f16_t)v.z, (f16_t)v.w};
  ((f16x4*)out)[i] = o;
}

// ---------- fused X prep: Xb = f16(X) row-major, Xt = f16(X)^T per batch ----------
__global__ __launch_bounds__(256) void xprep_kernel(const float* __restrict__ in,
                                                    f16_t* __restrict__ xb,
                                                    f16_t* __restrict__ xt) {
  __shared__ float tile[32][33];
  int b = blockIdx.z;
  const float* inb = in + (size_t)b * 2048 * 1024;
  f16_t* xbb = xb + (size_t)b * 2048 * 1024;
  f16_t* xtb = xt + (size_t)b * 1024 * 2048;
  int tx = threadIdx.x, ty = threadIdx.y;  // 32 x 8
  int c0 = blockIdx.x * 32, r0 = blockIdx.y * 32;
#pragma unroll
  for (int i = 0; i < 32; i += 8) {
    float v = inb[(size_t)(r0 + ty + i) * 1024 + (c0 + tx)];
    tile[ty + i][tx] = v;
    xbb[(size_t)(r0 + ty + i) * 1024 + (c0 + tx)] = (f16_t)v;
  }
  __syncthreads();
#pragma unroll
  for (int i = 0; i < 32; i += 8)
    xtb[(size_t)(c0 + ty + i) * 2048 + (r0 + tx)] = (f16_t)tile[tx][ty + i];
}

// ---------- bias-prep: wqbk[r]=Wq[r]·bk, wkbq[r]=Wk[r]·bq, c0=bq·bk ----------
__global__ __launch_bounds__(256) void wvec_kernel(const float* __restrict__ Wq,
                                                   const float* __restrict__ bq,
                                                   const float* __restrict__ Wk,
                                                   const float* __restrict__ bk,
                                                   float* __restrict__ wqbk,
                                                   float* __restrict__ wkbq,
                                                   float* __restrict__ c0) {
  __shared__ float red[4];
  int bid = blockIdx.x, tid = threadIdx.x;
  const float* rowp; const float* vecp; float* outp;
  if (bid < 1024)      { rowp = Wq + (size_t)bid * 1024; vecp = bk; outp = wqbk + bid; }
  else if (bid < 2048) { rowp = Wk + (size_t)(bid - 1024) * 1024; vecp = bq; outp = wkbq + (bid - 1024); }
  else                 { rowp = bq; vecp = bk; outp = c0; }
  float4 a = ((const float4*)rowp)[tid];
  float4 b = ((const float4*)vecp)[tid];
  float s = a.x * b.x + a.y * b.y + a.z * b.z + a.w * b.w;
#pragma unroll
  for (int off = 32; off > 0; off >>= 1) s += __shfl_xor(s, off, 64);
  if ((tid & 63) == 0) red[tid >> 6] = s;
  __syncthreads();
  if (tid == 0) *outp = red[0] + red[1] + red[2] + red[3];
}

// ---------- cq[m]=X[m]·wqbk, ck[m]=X[m]·wkbq (one block per row) ----------
__global__ __launch_bounds__(256) void cqck_kernel(const float* __restrict__ X,
                                                   const float* __restrict__ wqbk,
                                                   const float* __restrict__ wkbq,
                                                   float* __restrict__ cq,
                                                   float* __restrict__ ck) {
  __shared__ float r1[4], r2[4];
  int m = blockIdx.x, tid = threadIdx.x;
  float4 x = ((const float4*)(X + (size_t)m * 1024))[tid];
  float4 a = ((const float4*)wqbk)[tid];
  float4 b = ((const float4*)wkbq)[tid];
  float s1 = x.x * a.x + x.y * a.y + x.z * a.z + x.w * a.w;
  float s2 = x.x * b.x + x.y * b.y + x.z * b.z + x.w * b.w;
#pragma unroll
  for (int off = 32; off > 0; off >>= 1) { s1 += __shfl_xor(s1, off, 64); s2 += __shfl_xor(s2, off, 64); }
  if ((tid & 63) == 0) { r1[tid >> 6] = s1; r2[tid >> 6] = s2; }
  __syncthreads();
  if (tid == 0) {
    cq[m] = r1[0] + r1[1] + r1[2] + r1[3];
    ck[m] = r2[0] + r2[1] + r2[2] + r2[3];
  }
}

// ---------- 128x128 MFMA GEMM (R1 structure) -- used only for the tiny 1024^3 Wkq GEMM ----------
__global__ __launch_bounds__(256) void gemm_bt_kernel(
    const f16_t* __restrict__ A, const f16_t* __restrict__ Bt, f16_t* __restrict__ C,
    int lda, int ldb, int ldc, int K) {
  __shared__ f16_t As[2][128 * 64];
  __shared__ f16_t Bs[2][128 * 64];

  const int tid = threadIdx.x;
  const int lane = tid & 63;
  const int wv = tid >> 6;
  const int m16 = lane & 15;
  const int quad = lane >> 4;
  const int wr = (wv >> 1) * 64;
  const int wc = (wv & 1) * 64;

  const f16_t* Ab = A + (size_t)blockIdx.x * 128 * lda;
  const f16_t* Bb = Bt + (size_t)blockIdx.y * 128 * ldb;

  const int lr8 = lane >> 3;
  const int ch8 = (lane & 7) ^ lr8;
  const f16_t* gA[4]; const f16_t* gB[4];
  f16_t* lA[4]; f16_t* lB[4];
#pragma unroll
  for (int j = 0; j < 4; ++j) {
    int row = wv * 32 + j * 8 + lr8;
    gA[j] = Ab + (size_t)row * lda + ch8 * 8;
    gB[j] = Bb + (size_t)row * ldb + ch8 * 8;
    lA[j] = &As[0][(wv * 32 + j * 8) * 64];
    lB[j] = &Bs[0][(wv * 32 + j * 8) * 64];
  }

  int aoff[4], boff[4], swz[2];
#pragma unroll
  for (int t = 0; t < 4; ++t) {
    aoff[t] = (wr + t * 16 + m16) * 64;
    boff[t] = (wc + t * 16 + m16) * 64;
  }
#pragma unroll
  for (int s = 0; s < 2; ++s)
    swz[s] = (((s << 2) | quad) ^ (m16 & 7)) * 8;

  f32x4 acc[4][4] = {};

#define STAGE(BUF, KOFF)                                       \
  _Pragma("unroll")                                            \
  for (int j = 0; j < 4; ++j) {                                \
    gload_lds16(gA[j] + (KOFF), lA[j] + (BUF) * (128 * 64));   \
    gload_lds16(gB[j] + (KOFF), lB[j] + (BUF) * (128 * 64));   \
  }

#define COMPUTE(BUF)                                                           \
  _Pragma("unroll")                                                            \
  for (int s = 0; s < 2; ++s) {                                                \
    f16x8 af[4], bfr[4];                                                       \
    _Pragma("unroll")                                                          \
    for (int t = 0; t < 4; ++t) {                                              \
      af[t]  = *(const f16x8*)&As[BUF][aoff[t] + swz[s]];                      \
      bfr[t] = *(const f16x8*)&Bs[BUF][boff[t] + swz[s]];                      \
    }                                                                          \
    _Pragma("unroll")                                                          \
    for (int rt = 0; rt < 4; ++rt)                                             \
      _Pragma("unroll")                                                        \
      for (int ct = 0; ct < 4; ++ct)                                           \
        acc[rt][ct] = __builtin_amdgcn_mfma_f32_16x16x32_f16(af[rt], bfr[ct],  \
                                                             acc[rt][ct], 0, 0, 0); \
  }

  STAGE(0, 0);
  __syncthreads();
  for (int k0 = 0; k0 < K; k0 += 128) {
    STAGE(1, k0 + 64);
    COMPUTE(0);
    __syncthreads();
    if (k0 + 128 < K) STAGE(0, k0 + 128);
    COMPUTE(1);
    __syncthreads();
  }
#undef STAGE
#undef COMPUTE

  const int row0 = blockIdx.x * 128 + wr + quad * 4;
  const int col0 = blockIdx.y * 128 + wc + m16;
#pragma unroll
  for (int ct = 0; ct < 4; ++ct)
#pragma unroll
    for (int rt = 0; rt < 4; ++rt)
#pragma unroll
      for (int r = 0; r < 4; ++r)
        C[(size_t)(row0 + rt * 16 + r) * ldc + col0 + ct * 16] = (f16_t)acc[rt][ct][r];
}

// ---------- 256x256 MFMA GEMM, C = A[MxK]*Bt[NxK]^T ----------
// R7 = R6 (verified: 117us mode-1, MfmaUtil 24.5, WRITE at floor) + T1
// bijective XCD swizzle. 1D grid; in-kernel remap so each XCD gets a
// CONTIGUOUS chunk of tiles (B-panels L2-resident across consecutive blocks,
// A-panels L3-hot) -> targets the 167MB-vs-64MB-floor FETCH overfetch.
// swz = (lin&7)*(nwg/8) + (lin>>3); requires nwg % 8 == 0 (all call sites:
// 512/256/256). Decompose x-fastest (matches old 3D order within a chunk).
// Everything else byte-identical to R6: double-buffered 2-phase loop, one
// __syncthreads per 64-K step, XOR swizzle (0 bank conflicts), mr-outer
// epilogues. 512 threads = 8 waves (2M x 4N); per-wave out 128x64 = acc[8][4].
// Requires K % 128 == 0, M,N multiples of 256.
// mode 0: plain f16 store; mode 1: masked exp + row-sum partials; mode 2: *invl
__global__ __launch_bounds__(512) void gemm256_kernel(
    const f16_t* __restrict__ A, const f16_t* __restrict__ Bt, f16_t* __restrict__ C,
    const float* __restrict__ cq, const float* __restrict__ ck, const float* __restrict__ c0p,
    const int* __restrict__ mask, const float* __restrict__ invl, float* __restrict__ lpart,
    int lda, int ldb, int ldc, int K, float scale, int mode,
    size_t sA, size_t sB, size_t sC, int gx, int gy) {
  __shared__ f16_t As[2][256 * 64];   // 64 KB
  __shared__ f16_t Bs[2][256 * 64];   // 64 KB

  // ---- XCD-aware block remap (T1, bijective since nwg % 8 == 0) ----
  const int nwg = gridDim.x;
  const int lin = blockIdx.x;
  const int swzid = (lin & 7) * (nwg >> 3) + (lin >> 3);
  const int bx = swzid % gx;
  const int rem = swzid / gx;
  const int by = rem % gy;
  const int bz = rem / gy;

  const int tid = threadIdx.x;
  const int lane = tid & 63;
  const int wid = tid >> 6;        // 0..7
  const int wm = wid >> 2;         // 0..1  (row half)
  const int wn = wid & 3;          // 0..3  (col quarter)
  const int m16 = lane & 15;
  const int quad = lane >> 4;

  const f16_t* Ab = A + bz * sA + (size_t)bx * 256 * lda;
  const f16_t* Bb = Bt + bz * sB + (size_t)by * 256 * ldb;

  // staging: wave wid covers rows wid*32 + j*8 + (0..7); lane = lr8*8 + slot;
  // content chunk = slot ^ (row&7)  (XOR swizzle).
  const int lr8 = lane >> 3;
  const int ch8 = (lane & 7) ^ lr8;
  const f16_t* gA = Ab + (size_t)(wid * 32 + lr8) * lda + ch8 * 8;
  const f16_t* gB = Bb + (size_t)(wid * 32 + lr8) * ldb + ch8 * 8;
  char* ldsA = (char*)As + wid * 4096;   // + buf*32768
  char* ldsB = (char*)Bs + wid * 4096;

  // fragment-read offsets (elements within one buffer): row r, chunk c ->
  // r*64 + (c^(r&7))*8
  int aoff[8], boff[4], swz[2];
#pragma unroll
  for (int mr = 0; mr < 8; ++mr) aoff[mr] = (wm * 128 + mr * 16 + m16) * 64;
#pragma unroll
  for (int nr = 0; nr < 4; ++nr) boff[nr] = (wn * 64 + nr * 16 + m16) * 64;
#pragma unroll
  for (int s = 0; s < 2; ++s)
    swz[s] = (((s << 2) | quad) ^ (m16 & 7)) * 8;

  f32x4 acc[8][4] = {};

#define STAGE(BUF, KOFF)                                 \
  stage8(gA + (KOFF), lda, ldsA + (BUF) * 32768);        \
  stage8(gB + (KOFF), ldb, ldsB + (BUF) * 32768);

#define COMPUTE(BUF)                                                           \
  _Pragma("unroll")                                                            \
  for (int s = 0; s < 2; ++s) {                                                \
    f16x8 af[8], bf[4];                                                        \
    _Pragma("unroll")                                                          \
    for (int mr = 0; mr < 8; ++mr) af[mr] = *(const f16x8*)&As[BUF][aoff[mr] + swz[s]]; \
    _Pragma("unroll")                                                          \
    for (int nr = 0; nr < 4; ++nr) bf[nr] = *(const f16x8*)&Bs[BUF][boff[nr] + swz[s]]; \
    _Pragma("unroll")                                                          \
    for (int mr = 0; mr < 8; ++mr)                                             \
      _Pragma("unroll")                                                        \
      for (int nr = 0; nr < 4; ++nr)                                           \
        acc[mr][nr] = __builtin_amdgcn_mfma_f32_16x16x32_f16(af[mr], bf[nr],   \
                                                             acc[mr][nr], 0, 0, 0); \
  }

  STAGE(0, 0);
  __syncthreads();
  for (int k0 = 0; k0 < K; k0 += 128) {
    STAGE(1, k0 + 64);
    COMPUTE(0);
    __syncthreads();
    if (k0 + 128 < K) STAGE(0, k0 + 128);
    COMPUTE(1);
    __syncthreads();
  }
#undef STAGE
#undef COMPUTE

  // epilogue; C/D layout: col = lane&15, row = quad*4 + reg  [m89-verified]
  // mr-outer/nr-inner: 4 consecutive stores cover a row's 128B segment.
  f16_t* Cb = C + bz * sC;
  const int row0 = bx * 256 + wm * 128 + quad * 4;
  const int col0 = by * 256 + wn * 64 + m16;
  if (mode == 0) {
#pragma unroll
    for (int mr = 0; mr < 8; ++mr)
#pragma unroll
      for (int r = 0; r < 4; ++r) {
        f16_t* rowp = Cb + (size_t)(row0 + mr * 16 + r) * ldc + col0;
#pragma unroll
        for (int nr = 0; nr < 4; ++nr)
          rowp[nr * 16] = (f16_t)acc[mr][nr][r];
      }
  } else if (mode == 1) {
    const int* mp = mask + bz * 2048;
    const size_t rowg0 = bz * 2048 + row0;
    const float c0 = *c0p;
    float ckv[4]; bool keep[4];
#pragma unroll
    for (int nr = 0; nr < 4; ++nr) {
      int col = col0 + nr * 16;
      keep[nr] = (mp[col] != 0);
      ckv[nr] = ck[bz * 2048 + col];
    }
    float rsum[8][4];
#pragma unroll
    for (int mr = 0; mr < 8; ++mr)
#pragma unroll
      for (int r = 0; r < 4; ++r) {
        float cqv = cq[rowg0 + mr * 16 + r];
        f16_t* rowp = Cb + (size_t)(row0 + mr * 16 + r) * ldc + col0;
        float rs_ = 0.f;
#pragma unroll
        for (int nr = 0; nr < 4; ++nr) {
          float p = keep[nr] ? __expf((acc[mr][nr][r] + cqv + ckv[nr] + c0) * scale) : 0.f;
          rs_ += p;
          rowp[nr * 16] = (f16_t)p;
        }
        rsum[mr][r] = rs_;
      }
    const int chunk = by * 4 + wn;
#pragma unroll
    for (int mr = 0; mr < 8; ++mr)
#pragma unroll
      for (int r = 0; r < 4; ++r) {
        float v = rsum[mr][r];
        v += __shfl_xor(v, 1, 16);
        v += __shfl_xor(v, 2, 16);
        v += __shfl_xor(v, 4, 16);
        v += __shfl_xor(v, 8, 16);
        if (m16 == 0) lpart[(rowg0 + mr * 16 + r) * 32 + chunk] = v;
      }
  } else {
    const size_t rowg0 = bz * 2048 + row0;
#pragma unroll
    for (int mr = 0; mr < 8; ++mr)
#pragma unroll
      for (int r = 0; r < 4; ++r) {
        float il = invl[rowg0 + mr * 16 + r];
        f16_t* rowp = Cb + (size_t)(row0 + mr * 16 + r) * ldc + col0;
#pragma unroll
        for (int nr = 0; nr < 4; ++nr)
          rowp[nr * 16] = (f16_t)(acc[mr][nr][r] * il);
      }
  }
}

// ---------- l reduce: invl[m] = 1 / sum(lpart[m][0..32)) ----------
__global__ __launch_bounds__(256) void lreduce_kernel(const float* __restrict__ lpart,
                                                      float* __restrict__ invl) {
  int m = blockIdx.x * 256 + threadIdx.x;
  const float4* p = (const float4*)(lpart + (size_t)m * 32);
  float s = 0.f;
#pragma unroll
  for (int j = 0; j < 8; ++j) {
    float4 v = p[j];
    s += v.x + v.y + v.z + v.w;
  }
  invl[m] = 1.0f / fmaxf(s, 1e-30f);
}

// ---------- residual + LayerNorm: out[row] = LN(X[row] + Ctx[row]) ----------
__global__ __launch_bounds__(256) void ln_kernel(const float* __restrict__ X,
                                                 const f16_t* __restrict__ Ctx,
                                                 const float* __restrict__ gamma,
                                                 const float* __restrict__ beta,
                                                 float* __restrict__ out) {
  __shared__ float r1[4], r2[4];
  const int tid = threadIdx.x;
  const size_t base = (size_t)blockIdx.x * 1024;
  float4 xv = ((const float4*)(X + base))[tid];
  f16x4 cv = ((const f16x4*)(Ctx + base))[tid];
  float v0 = xv.x + (float)cv[0];
  float v1 = xv.y + (float)cv[1];
  float v2 = xv.z + (float)cv[2];
  float v3 = xv.w + (float)cv[3];
  float s1 = v0 + v1 + v2 + v3;
  float s2 = v0 * v0 + v1 * v1 + v2 * v2 + v3 * v3;
#pragma unroll
  for (int off = 32; off > 0; off >>= 1) {
    s1 += __shfl_xor(s1, off, 64);
    s2 += __shfl_xor(s2, off, 64);
  }
  if ((tid & 63) == 0) { r1[tid >> 6] = s1; r2[tid >> 6] = s2; }
  __syncthreads();
  s1 = r1[0] + r1[1] + r1[2] + r1[3];
  s2 = r2[0] + r2[1] + r2[2] + r2[3];
  float mu = s1 * (1.0f / 1024.0f);
  float var = s2 * (1.0f / 1024.0f) - mu * mu;
  float rs = rsqrtf(fmaxf(var, 0.0f) + LN_EPS);
  float4 gv = ((const float4*)gamma)[tid];
  float4 bv = ((const float4*)beta)[tid];
  float4 o;
  o.x = (v0 - mu) * rs * gv.x + bv.x;
  o.y = (v1 - mu) * rs * gv.y + bv.y;
  o.z = (v2 - mu) * rs * gv.z + bv.z;
  o.w = (v3 - mu) * rs * gv.w + bv.w;
  ((float4*)(out + base))[tid] = o;
}

// ---------- launch ----------
extern "C" void kernel_launch(void* const* d_in, const int* in_sizes, int n_in,
                              void* d_out, int out_size, void* d_ws, size_t ws_size,
                              hipStream_t stream) {
  const float* X     = (const float*)d_in[0];  // [8,2048,1024]
  const int*   masks = (const int*)d_in[1];    // [8,2048]
  const float* Wq    = (const float*)d_in[2];  // [1024,1024]
  const float* bq    = (const float*)d_in[3];
  const float* Wk    = (const float*)d_in[4];
  const float* bk    = (const float*)d_in[5];
  const float* gamma = (const float*)d_in[6];
  const float* beta  = (const float*)d_in[7];
  float* out = (float*)d_out;

  if (ws_size < 115343360u) return;  // need ~110 MiB
  char* ws = (char*)d_ws;
  f16_t* Xb   = (f16_t*)(ws + 0);           // [16384][1024] f16 (later Ctx)
  f16_t* Xt   = (f16_t*)(ws + 33554432);    // [8][1024][2048] f16
  f16_t* T    = (f16_t*)(ws + 67108864);    // [16384][1024] f16
  f16_t* Wqf  = (f16_t*)(ws + 100663296);   // [1024][1024] f16
  f16_t* Wkf  = (f16_t*)(ws + 102760448);   // [1024][1024] f16
  f16_t* Wkq  = (f16_t*)(ws + 104857600);   // [1024][1024] f16 (Wk·Wq^T)
  float* lpart= (float*)(ws + 106954752);   // [16384][32] f32
  float* cq   = (float*)(ws + 109051904);   // [16384]
  float* ck   = (float*)(ws + 109117440);   // [16384]
  float* invl = (float*)(ws + 109182976);   // [16384]
  float* wqbk = (float*)(ws + 109248512);   // [1024]
  float* wkbq = (float*)(ws + 109252608);   // [1024]
  float* c0   = (float*)(ws + 109256704);   // [1]
  f16_t* Ctx  = Xb;
  f16_t* probs = (f16_t*)d_out;             // [8][2048][2048] f16 == 64 MiB

  const size_t SH = 2048u * 1024u;
  const size_t SS = 2048u * 2048u;
  const size_t HS = 1024u * 2048u;

  // 1. prep: fused cast+transpose of X, W casts, bias vectors
  xprep_kernel<<<dim3(32, 64, 8), dim3(32, 8), 0, stream>>>(X, Xb, Xt);
  cast_f16_kernel<<<1024, 256, 0, stream>>>(Wq, Wqf);
  cast_f16_kernel<<<1024, 256, 0, stream>>>(Wk, Wkf);
  wvec_kernel<<<2049, 256, 0, stream>>>(Wq, bq, Wk, bk, wqbk, wkbq, c0);
  cqck_kernel<<<16384, 256, 0, stream>>>(X, wqbk, wkbq, cq, ck);

  // 2. Wkq = Wk · Wq^T   (tiny 1024^3, old 128^2 kernel)
  gemm_bt_kernel<<<dim3(8, 8, 1), 256, 0, stream>>>(
      Wkf, Wqf, Wkq, 1024, 1024, 1024, 1024);

  // 3. T = Xb · Wkq^T   (M=16384, N=1024, K=1024) -- 1D grid 256 (= 64x4x1)
  gemm256_kernel<<<256, 512, 0, stream>>>(
      Xb, Wkq, T, nullptr, nullptr, nullptr, nullptr, nullptr, nullptr,
      1024, 1024, 1024, 1024, 0.f, 0, 0, 0, 0, 64, 4);

  // 4. p = exp((T·X^T + bias-terms)/32) masked + row-sum partials -- 512 (=8x8x8)
  gemm256_kernel<<<512, 512, 0, stream>>>(
      T, Xb, probs, cq, ck, c0, masks, nullptr, lpart,
      1024, 1024, 2048, 1024, 0.03125f, 1, SH, SH, SS, 8, 8);

  // 5. invl = 1/rowsum
  lreduce_kernel<<<64, 256, 0, stream>>>(lpart, invl);

  // 6. context = (p/l) @ X   (per batch M=2048,N=1024,K=2048) -- 256 (=8x4x8)
  gemm256_kernel<<<256, 512, 0, stream>>>(
      probs, Xt, Ctx, nullptr, nullptr, nullptr, nullptr, invl, nullptr,
      2048, 2048, 1024, 2048, 0.f, 2, SS, HS, SH, 8, 4);

  // 7. out = LayerNorm(X + context)
  ln_kernel<<<16384, 256, 0, stream>>>(X, Ctx, gamma, beta, out);
}

// Round 8
// 426.011 us; speedup vs baseline: 1.0072x; 1.0072x over previous
//
#include <hip/hip_runtime.h>
#include <stdint.h>
#include <stddef.h>

// ---------- types ----------
typedef _Float16 f16_t;
typedef _Float16 f16x8 __attribute__((ext_vector_type(8)));
typedef _Float16 f16x4 __attribute__((ext_vector_type(4)));
typedef float    f32x4 __attribute__((ext_vector_type(4)));

#define AS_G __attribute__((address_space(1)))
#define AS_L __attribute__((address_space(3)))

__device__ __forceinline__ void gload_lds16(const void* g, void* l) {
  // async global->LDS, 16B per lane; HW writes lds_base + lane*16
  __builtin_amdgcn_global_load_lds((const AS_G uint32_t*)g, (AS_L uint32_t*)l, 16, 0, 0);
}

// stage 32 rows x 64 f16 (4 calls of 8 rows) for one wave
__device__ __forceinline__ void stage8(const f16_t* g, int ld, char* l) {
#pragma unroll
  for (int j = 0; j < 4; ++j)
    gload_lds16(g + (size_t)(j * 8) * ld, l + j * 1024);
}

// stage 32 rows x 32 f16 (2 calls of 16 rows) for one wave (BK=32 path)
__device__ __forceinline__ void stage4(const f16_t* g, int ld, char* l) {
#pragma unroll
  for (int j = 0; j < 2; ++j)
    gload_lds16(g + (size_t)(j * 16) * ld, l + j * 1024);
}

#define LN_EPS 1e-12f

// ---------- cast fp32 -> f16 (vectorized x4) ----------
__global__ __launch_bounds__(256) void cast_f16_kernel(const float* __restrict__ in,
                                                       f16_t* __restrict__ out) {
  int i = blockIdx.x * 256 + threadIdx.x;
  float4 v = ((const float4*)in)[i];
  f16x4 o = {(f16_t)v.x, (f16_t)v.y, (f16_t)v.z, (f16_t)v.w};
  ((f16x4*)out)[i] = o;
}

// ---------- fused X prep: Xb = f16(X) row-major, Xt = f16(X)^T per batch ----------
__global__ __launch_bounds__(256) void xprep_kernel(const float* __restrict__ in,
                                                    f16_t* __restrict__ xb,
                                                    f16_t* __restrict__ xt) {
  __shared__ float tile[32][33];
  int b = blockIdx.z;
  const float* inb = in + (size_t)b * 2048 * 1024;
  f16_t* xbb = xb + (size_t)b * 2048 * 1024;
  f16_t* xtb = xt + (size_t)b * 1024 * 2048;
  int tx = threadIdx.x, ty = threadIdx.y;  // 32 x 8
  int c0 = blockIdx.x * 32, r0 = blockIdx.y * 32;
#pragma unroll
  for (int i = 0; i < 32; i += 8) {
    float v = inb[(size_t)(r0 + ty + i) * 1024 + (c0 + tx)];
    tile[ty + i][tx] = v;
    xbb[(size_t)(r0 + ty + i) * 1024 + (c0 + tx)] = (f16_t)v;
  }
  __syncthreads();
#pragma unroll
  for (int i = 0; i < 32; i += 8)
    xtb[(size_t)(c0 + ty + i) * 2048 + (r0 + tx)] = (f16_t)tile[tx][ty + i];
}

// ---------- bias-prep: wqbk[r]=Wq[r]·bk, wkbq[r]=Wk[r]·bq, c0=bq·bk ----------
__global__ __launch_bounds__(256) void wvec_kernel(const float* __restrict__ Wq,
                                                   const float* __restrict__ bq,
                                                   const float* __restrict__ Wk,
                                                   const float* __restrict__ bk,
                                                   float* __restrict__ wqbk,
                                                   float* __restrict__ wkbq,
                                                   float* __restrict__ c0) {
  __shared__ float red[4];
  int bid = blockIdx.x, tid = threadIdx.x;
  const float* rowp; const float* vecp; float* outp;
  if (bid < 1024)      { rowp = Wq + (size_t)bid * 1024; vecp = bk; outp = wqbk + bid; }
  else if (bid < 2048) { rowp = Wk + (size_t)(bid - 1024) * 1024; vecp = bq; outp = wkbq + (bid - 1024); }
  else                 { rowp = bq; vecp = bk; outp = c0; }
  float4 a = ((const float4*)rowp)[tid];
  float4 b = ((const float4*)vecp)[tid];
  float s = a.x * b.x + a.y * b.y + a.z * b.z + a.w * b.w;
#pragma unroll
  for (int off = 32; off > 0; off >>= 1) s += __shfl_xor(s, off, 64);
  if ((tid & 63) == 0) red[tid >> 6] = s;
  __syncthreads();
  if (tid == 0) *outp = red[0] + red[1] + red[2] + red[3];
}

// ---------- cq[m]=X[m]·wqbk, ck[m]=X[m]·wkbq (one block per row) ----------
__global__ __launch_bounds__(256) void cqck_kernel(const float* __restrict__ X,
                                                   const float* __restrict__ wqbk,
                                                   const float* __restrict__ wkbq,
                                                   float* __restrict__ cq,
                                                   float* __restrict__ ck) {
  __shared__ float r1[4], r2[4];
  int m = blockIdx.x, tid = threadIdx.x;
  float4 x = ((const float4*)(X + (size_t)m * 1024))[tid];
  float4 a = ((const float4*)wqbk)[tid];
  float4 b = ((const float4*)wkbq)[tid];
  float s1 = x.x * a.x + x.y * a.y + x.z * a.z + x.w * a.w;
  float s2 = x.x * b.x + x.y * b.y + x.z * b.z + x.w * b.w;
#pragma unroll
  for (int off = 32; off > 0; off >>= 1) { s1 += __shfl_xor(s1, off, 64); s2 += __shfl_xor(s2, off, 64); }
  if ((tid & 63) == 0) { r1[tid >> 6] = s1; r2[tid >> 6] = s2; }
  __syncthreads();
  if (tid == 0) {
    cq[m] = r1[0] + r1[1] + r1[2] + r1[3];
    ck[m] = r2[0] + r2[1] + r2[2] + r2[3];
  }
}

// ---------- 128x128 MFMA GEMM (R1 structure) -- used only for the tiny 1024^3 Wkq GEMM ----------
__global__ __launch_bounds__(256) void gemm_bt_kernel(
    const f16_t* __restrict__ A, const f16_t* __restrict__ Bt, f16_t* __restrict__ C,
    int lda, int ldb, int ldc, int K) {
  __shared__ f16_t As[2][128 * 64];
  __shared__ f16_t Bs[2][128 * 64];

  const int tid = threadIdx.x;
  const int lane = tid & 63;
  const int wv = tid >> 6;
  const int m16 = lane & 15;
  const int quad = lane >> 4;
  const int wr = (wv >> 1) * 64;
  const int wc = (wv & 1) * 64;

  const f16_t* Ab = A + (size_t)blockIdx.x * 128 * lda;
  const f16_t* Bb = Bt + (size_t)blockIdx.y * 128 * ldb;

  const int lr8 = lane >> 3;
  const int ch8 = (lane & 7) ^ lr8;
  const f16_t* gA[4]; const f16_t* gB[4];
  f16_t* lA[4]; f16_t* lB[4];
#pragma unroll
  for (int j = 0; j < 4; ++j) {
    int row = wv * 32 + j * 8 + lr8;
    gA[j] = Ab + (size_t)row * lda + ch8 * 8;
    gB[j] = Bb + (size_t)row * ldb + ch8 * 8;
    lA[j] = &As[0][(wv * 32 + j * 8) * 64];
    lB[j] = &Bs[0][(wv * 32 + j * 8) * 64];
  }

  int aoff[4], boff[4], swz[2];
#pragma unroll
  for (int t = 0; t < 4; ++t) {
    aoff[t] = (wr + t * 16 + m16) * 64;
    boff[t] = (wc + t * 16 + m16) * 64;
  }
#pragma unroll
  for (int s = 0; s < 2; ++s)
    swz[s] = (((s << 2) | quad) ^ (m16 & 7)) * 8;

  f32x4 acc[4][4] = {};

#define STAGE(BUF, KOFF)                                       \
  _Pragma("unroll")                                            \
  for (int j = 0; j < 4; ++j) {                                \
    gload_lds16(gA[j] + (KOFF), lA[j] + (BUF) * (128 * 64));   \
    gload_lds16(gB[j] + (KOFF), lB[j] + (BUF) * (128 * 64));   \
  }

#define COMPUTE(BUF)                                                           \
  _Pragma("unroll")                                                            \
  for (int s = 0; s < 2; ++s) {                                                \
    f16x8 af[4], bfr[4];                                                       \
    _Pragma("unroll")                                                          \
    for (int t = 0; t < 4; ++t) {                                              \
      af[t]  = *(const f16x8*)&As[BUF][aoff[t] + swz[s]];                      \
      bfr[t] = *(const f16x8*)&Bs[BUF][boff[t] + swz[s]];                      \
    }                                                                          \
    _Pragma("unroll")                                                          \
    for (int rt = 0; rt < 4; ++rt)                                             \
      _Pragma("unroll")                                                        \
      for (int ct = 0; ct < 4; ++ct)                                           \
        acc[rt][ct] = __builtin_amdgcn_mfma_f32_16x16x32_f16(af[rt], bfr[ct],  \
                                                             acc[rt][ct], 0, 0, 0); \
  }

  STAGE(0, 0);
  __syncthreads();
  for (int k0 = 0; k0 < K; k0 += 128) {
    STAGE(1, k0 + 64);
    COMPUTE(0);
    __syncthreads();
    if (k0 + 128 < K) STAGE(0, k0 + 128);
    COMPUTE(1);
    __syncthreads();
  }
#undef STAGE
#undef COMPUTE

  const int row0 = blockIdx.x * 128 + wr + quad * 4;
  const int col0 = blockIdx.y * 128 + wc + m16;
#pragma unroll
  for (int ct = 0; ct < 4; ++ct)
#pragma unroll
    for (int rt = 0; rt < 4; ++rt)
#pragma unroll
      for (int r = 0; r < 4; ++r)
        C[(size_t)(row0 + rt * 16 + r) * ldc + col0 + ct * 16] = (f16_t)acc[rt][ct][r];
}

// ---------- 256x256 MFMA GEMM, BK=64 (R6/R7-verified) -- steps 3 and 6 ----------
// Double-buffered 2-phase, one __syncthreads per 64-K step, XOR swizzle
// (chunk c of row r at slot c^(r&7), 0 bank conflicts measured), T1 XCD
// swizzle (FETCH 163->58MB verified), mr-outer epilogues (WRITE at floor).
// 512 threads = 8 waves (2M x 4N); per-wave out 128x64 = acc[8][4].
// Requires K % 128 == 0, M,N multiples of 256, grid % 8 == 0.
// mode 0: plain f16 store; mode 2: acc*invl[row] -> f16
__global__ __launch_bounds__(512) void gemm256_kernel(
    const f16_t* __restrict__ A, const f16_t* __restrict__ Bt, f16_t* __restrict__ C,
    const float* __restrict__ invl,
    int lda, int ldb, int ldc, int K, int mode,
    size_t sA, size_t sB, size_t sC, int gx, int gy) {
  __shared__ f16_t As[2][256 * 64];   // 64 KB
  __shared__ f16_t Bs[2][256 * 64];   // 64 KB

  // ---- XCD-aware block remap (T1, bijective since nwg % 8 == 0) ----
  const int nwg = gridDim.x;
  const int lin = blockIdx.x;
  const int swzid = (lin & 7) * (nwg >> 3) + (lin >> 3);
  const int bx = swzid % gx;
  const int rem = swzid / gx;
  const int by = rem % gy;
  const int bz = rem / gy;

  const int tid = threadIdx.x;
  const int lane = tid & 63;
  const int wid = tid >> 6;        // 0..7
  const int wm = wid >> 2;         // 0..1  (row half)
  const int wn = wid & 3;          // 0..3  (col quarter)
  const int m16 = lane & 15;
  const int quad = lane >> 4;

  const f16_t* Ab = A + bz * sA + (size_t)bx * 256 * lda;
  const f16_t* Bb = Bt + bz * sB + (size_t)by * 256 * ldb;

  const int lr8 = lane >> 3;
  const int ch8 = (lane & 7) ^ lr8;
  const f16_t* gA = Ab + (size_t)(wid * 32 + lr8) * lda + ch8 * 8;
  const f16_t* gB = Bb + (size_t)(wid * 32 + lr8) * ldb + ch8 * 8;
  char* ldsA = (char*)As + wid * 4096;   // + buf*32768
  char* ldsB = (char*)Bs + wid * 4096;

  int aoff[8], boff[4], swz[2];
#pragma unroll
  for (int mr = 0; mr < 8; ++mr) aoff[mr] = (wm * 128 + mr * 16 + m16) * 64;
#pragma unroll
  for (int nr = 0; nr < 4; ++nr) boff[nr] = (wn * 64 + nr * 16 + m16) * 64;
#pragma unroll
  for (int s = 0; s < 2; ++s)
    swz[s] = (((s << 2) | quad) ^ (m16 & 7)) * 8;

  f32x4 acc[8][4] = {};

#define STAGE(BUF, KOFF)                                 \
  stage8(gA + (KOFF), lda, ldsA + (BUF) * 32768);        \
  stage8(gB + (KOFF), ldb, ldsB + (BUF) * 32768);

#define COMPUTE(BUF)                                                           \
  _Pragma("unroll")                                                            \
  for (int s = 0; s < 2; ++s) {                                                \
    f16x8 af[8], bf[4];                                                        \
    _Pragma("unroll")                                                          \
    for (int mr = 0; mr < 8; ++mr) af[mr] = *(const f16x8*)&As[BUF][aoff[mr] + swz[s]]; \
    _Pragma("unroll")                                                          \
    for (int nr = 0; nr < 4; ++nr) bf[nr] = *(const f16x8*)&Bs[BUF][boff[nr] + swz[s]]; \
    _Pragma("unroll")                                                          \
    for (int mr = 0; mr < 8; ++mr)                                             \
      _Pragma("unroll")                                                        \
      for (int nr = 0; nr < 4; ++nr)                                           \
        acc[mr][nr] = __builtin_amdgcn_mfma_f32_16x16x32_f16(af[mr], bf[nr],   \
                                                             acc[mr][nr], 0, 0, 0); \
  }

  STAGE(0, 0);
  __syncthreads();
  for (int k0 = 0; k0 < K; k0 += 128) {
    STAGE(1, k0 + 64);
    COMPUTE(0);
    __syncthreads();
    if (k0 + 128 < K) STAGE(0, k0 + 128);
    COMPUTE(1);
    __syncthreads();
  }
#undef STAGE
#undef COMPUTE

  // epilogue; C/D layout: col = lane&15, row = quad*4 + reg  [m89-verified]
  f16_t* Cb = C + bz * sC;
  const int row0 = bx * 256 + wm * 128 + quad * 4;
  const int col0 = by * 256 + wn * 64 + m16;
  if (mode == 0) {
#pragma unroll
    for (int mr = 0; mr < 8; ++mr)
#pragma unroll
      for (int r = 0; r < 4; ++r) {
        f16_t* rowp = Cb + (size_t)(row0 + mr * 16 + r) * ldc + col0;
#pragma unroll
        for (int nr = 0; nr < 4; ++nr)
          rowp[nr * 16] = (f16_t)acc[mr][nr][r];
      }
  } else {
    const size_t rowg0 = bz * 2048 + row0;
#pragma unroll
    for (int mr = 0; mr < 8; ++mr)
#pragma unroll
      for (int r = 0; r < 4; ++r) {
        float il = invl[rowg0 + mr * 16 + r];
        f16_t* rowp = Cb + (size_t)(row0 + mr * 16 + r) * ldc + col0;
#pragma unroll
        for (int nr = 0; nr < 4; ++nr)
          rowp[nr * 16] = (f16_t)(acc[mr][nr][r] * il);
      }
  }
}

// ---------- 256x256 MFMA GEMM, BK=32, mode-1 only -- step 4 ----------
// R8: halved LDS (2 bufs x 16KB x 2 arrays = 64 KiB) -> 2 blocks/CU
// co-residency: one block's MFMA fills the other's barrier-drain window
// (the m97-proven cross-block overlap mechanism; step 4's 512-block grid is
// the only call site that can exploit it). Same proven 2-phase __syncthreads
// discipline -- no raw barriers / inline asm (R3/R4 quarantine).
// BK=32 swizzle: 64B rows, 4 chunks; slot = chunk ^ ((row>>1)&3).
// Conflict-free under the consecutive-8-lane phase model (the model that
// correctly predicts BK64's measured 0 conflicts): lanes 0-7 hit byte
// {0,16}x interleave covering all 32 banks exactly once.
// Staging source pre-swizzle: call j covers 16 rows; lane l -> row l>>2,
// slot l&3, content chunk (l&3)^((l>>3)&3).
// p = exp((acc+cq[row]+ck[col]+c0)*scale) masked, + row-sum partials->lpart.
__global__ __launch_bounds__(512) void gemm256b32_kernel(
    const f16_t* __restrict__ A, const f16_t* __restrict__ Bt, f16_t* __restrict__ C,
    const float* __restrict__ cq, const float* __restrict__ ck, const float* __restrict__ c0p,
    const int* __restrict__ mask, float* __restrict__ lpart,
    int lda, int ldb, int ldc, int K, float scale,
    size_t sA, size_t sB, size_t sC, int gx, int gy) {
  __shared__ f16_t As[2][256 * 32];   // 16 KB per buf
  __shared__ f16_t Bs[2][256 * 32];

  // ---- XCD-aware block remap ----
  const int nwg = gridDim.x;
  const int lin = blockIdx.x;
  const int swzid = (lin & 7) * (nwg >> 3) + (lin >> 3);
  const int bx = swzid % gx;
  const int rem = swzid / gx;
  const int by = rem % gy;
  const int bz = rem / gy;

  const int tid = threadIdx.x;
  const int lane = tid & 63;
  const int wid = tid >> 6;        // 0..7
  const int wm = wid >> 2;         // 0..1
  const int wn = wid & 3;          // 0..3
  const int m16 = lane & 15;
  const int quad = lane >> 4;

  const f16_t* Ab = A + bz * sA + (size_t)bx * 256 * lda;
  const f16_t* Bb = Bt + bz * sB + (size_t)by * 256 * ldb;

  // staging: wave wid stages rows wid*32 + j*16 + (0..15); lane l -> row l>>2,
  // slot l&3; content chunk = (l&3) ^ ((l>>3)&3).
  const int lr16 = lane >> 2;
  const int ch4 = (lane & 3) ^ ((lane >> 3) & 3);
  const f16_t* gA = Ab + (size_t)(wid * 32 + lr16) * lda + ch4 * 8;
  const f16_t* gB = Bb + (size_t)(wid * 32 + lr16) * ldb + ch4 * 8;
  char* ldsA = (char*)As + wid * 2048;   // wave's 32 rows x 64B; + buf*16384
  char* ldsB = (char*)Bs + wid * 2048;

  // fragment reads: row r elems r*32; slot = quad ^ ((m16>>1)&3) (tile bases
  // are 16-aligned so (row>>1)&3 == (m16>>1)&3)
  int aoff[8], boff[4];
#pragma unroll
  for (int mr = 0; mr < 8; ++mr) aoff[mr] = (wm * 128 + mr * 16 + m16) * 32;
#pragma unroll
  for (int nr = 0; nr < 4; ++nr) boff[nr] = (wn * 64 + nr * 16 + m16) * 32;
  const int swzo = (quad ^ ((m16 >> 1) & 3)) * 8;

  f32x4 acc[8][4] = {};

#define STAGE32(BUF, KOFF)                               \
  stage4(gA + (KOFF), lda, ldsA + (BUF) * 16384);        \
  stage4(gB + (KOFF), ldb, ldsB + (BUF) * 16384);

#define COMPUTE32(BUF)                                                         \
  {                                                                            \
    f16x8 af[8], bf[4];                                                        \
    _Pragma("unroll")                                                          \
    for (int mr = 0; mr < 8; ++mr) af[mr] = *(const f16x8*)&As[BUF][aoff[mr] + swzo]; \
    _Pragma("unroll")                                                          \
    for (int nr = 0; nr < 4; ++nr) bf[nr] = *(const f16x8*)&Bs[BUF][boff[nr] + swzo]; \
    _Pragma("unroll")                                                          \
    for (int mr = 0; mr < 8; ++mr)                                             \
      _Pragma("unroll")                                                        \
      for (int nr = 0; nr < 4; ++nr)                                           \
        acc[mr][nr] = __builtin_amdgcn_mfma_f32_16x16x32_f16(af[mr], bf[nr],   \
                                                             acc[mr][nr], 0, 0, 0); \
  }

  STAGE32(0, 0);
  __syncthreads();
  for (int k0 = 0; k0 < K; k0 += 64) {   // K % 64 == 0 (call site: 1024)
    STAGE32(1, k0 + 32);
    COMPUTE32(0);
    __syncthreads();
    if (k0 + 64 < K) STAGE32(0, k0 + 64);
    COMPUTE32(1);
    __syncthreads();
  }
#undef STAGE32
#undef COMPUTE32

  // mode-1 epilogue (identical to R7's, mr-outer)
  f16_t* Cb = C + bz * sC;
  const int row0 = bx * 256 + wm * 128 + quad * 4;
  const int col0 = by * 256 + wn * 64 + m16;
  const int* mp = mask + bz * 2048;
  const size_t rowg0 = bz * 2048 + row0;
  const float c0 = *c0p;
  float ckv[4]; bool keep[4];
#pragma unroll
  for (int nr = 0; nr < 4; ++nr) {
    int col = col0 + nr * 16;
    keep[nr] = (mp[col] != 0);
    ckv[nr] = ck[bz * 2048 + col];
  }
  float rsum[8][4];
#pragma unroll
  for (int mr = 0; mr < 8; ++mr)
#pragma unroll
    for (int r = 0; r < 4; ++r) {
      float cqv = cq[rowg0 + mr * 16 + r];
      f16_t* rowp = Cb + (size_t)(row0 + mr * 16 + r) * ldc + col0;
      float rs_ = 0.f;
#pragma unroll
      for (int nr = 0; nr < 4; ++nr) {
        float p = keep[nr] ? __expf((acc[mr][nr][r] + cqv + ckv[nr] + c0) * scale) : 0.f;
        rs_ += p;
        rowp[nr * 16] = (f16_t)p;
      }
      rsum[mr][r] = rs_;
    }
  const int chunk = by * 4 + wn;
#pragma unroll
  for (int mr = 0; mr < 8; ++mr)
#pragma unroll
    for (int r = 0; r < 4; ++r) {
      float v = rsum[mr][r];
      v += __shfl_xor(v, 1, 16);
      v += __shfl_xor(v, 2, 16);
      v += __shfl_xor(v, 4, 16);
      v += __shfl_xor(v, 8, 16);
      if (m16 == 0) lpart[(rowg0 + mr * 16 + r) * 32 + chunk] = v;
    }
}

// ---------- l reduce: invl[m] = 1 / sum(lpart[m][0..32)) ----------
__global__ __launch_bounds__(256) void lreduce_kernel(const float* __restrict__ lpart,
                                                      float* __restrict__ invl) {
  int m = blockIdx.x * 256 + threadIdx.x;
  const float4* p = (const float4*)(lpart + (size_t)m * 32);
  float s = 0.f;
#pragma unroll
  for (int j = 0; j < 8; ++j) {
    float4 v = p[j];
    s += v.x + v.y + v.z + v.w;
  }
  invl[m] = 1.0f / fmaxf(s, 1e-30f);
}

// ---------- residual + LayerNorm: out[row] = LN(X[row] + Ctx[row]) ----------
__global__ __launch_bounds__(256) void ln_kernel(const float* __restrict__ X,
                                                 const f16_t* __restrict__ Ctx,
                                                 const float* __restrict__ gamma,
                                                 const float* __restrict__ beta,
                                                 float* __restrict__ out) {
  __shared__ float r1[4], r2[4];
  const int tid = threadIdx.x;
  const size_t base = (size_t)blockIdx.x * 1024;
  float4 xv = ((const float4*)(X + base))[tid];
  f16x4 cv = ((const f16x4*)(Ctx + base))[tid];
  float v0 = xv.x + (float)cv[0];
  float v1 = xv.y + (float)cv[1];
  float v2 = xv.z + (float)cv[2];
  float v3 = xv.w + (float)cv[3];
  float s1 = v0 + v1 + v2 + v3;
  float s2 = v0 * v0 + v1 * v1 + v2 * v2 + v3 * v3;
#pragma unroll
  for (int off = 32; off > 0; off >>= 1) {
    s1 += __shfl_xor(s1, off, 64);
    s2 += __shfl_xor(s2, off, 64);
  }
  if ((tid & 63) == 0) { r1[tid >> 6] = s1; r2[tid >> 6] = s2; }
  __syncthreads();
  s1 = r1[0] + r1[1] + r1[2] + r1[3];
  s2 = r2[0] + r2[1] + r2[2] + r2[3];
  float mu = s1 * (1.0f / 1024.0f);
  float var = s2 * (1.0f / 1024.0f) - mu * mu;
  float rs = rsqrtf(fmaxf(var, 0.0f) + LN_EPS);
  float4 gv = ((const float4*)gamma)[tid];
  float4 bv = ((const float4*)beta)[tid];
  float4 o;
  o.x = (v0 - mu) * rs * gv.x + bv.x;
  o.y = (v1 - mu) * rs * gv.y + bv.y;
  o.z = (v2 - mu) * rs * gv.z + bv.z;
  o.w = (v3 - mu) * rs * gv.w + bv.w;
  ((float4*)(out + base))[tid] = o;
}

// ---------- launch ----------
extern "C" void kernel_launch(void* const* d_in, const int* in_sizes, int n_in,
                              void* d_out, int out_size, void* d_ws, size_t ws_size,
                              hipStream_t stream) {
  const float* X     = (const float*)d_in[0];  // [8,2048,1024]
  const int*   masks = (const int*)d_in[1];    // [8,2048]
  const float* Wq    = (const float*)d_in[2];  // [1024,1024]
  const float* bq    = (const float*)d_in[3];
  const float* Wk    = (const float*)d_in[4];
  const float* bk    = (const float*)d_in[5];
  const float* gamma = (const float*)d_in[6];
  const float* beta  = (const float*)d_in[7];
  float* out = (float*)d_out;

  if (ws_size < 115343360u) return;  // need ~110 MiB
  char* ws = (char*)d_ws;
  f16_t* Xb   = (f16_t*)(ws + 0);           // [16384][1024] f16 (later Ctx)
  f16_t* Xt   = (f16_t*)(ws + 33554432);    // [8][1024][2048] f16
  f16_t* T    = (f16_t*)(ws + 67108864);    // [16384][1024] f16
  f16_t* Wqf  = (f16_t*)(ws + 100663296);   // [1024][1024] f16
  f16_t* Wkf  = (f16_t*)(ws + 102760448);   // [1024][1024] f16
  f16_t* Wkq  = (f16_t*)(ws + 104857600);   // [1024][1024] f16 (Wk·Wq^T)
  float* lpart= (float*)(ws + 106954752);   // [16384][32] f32
  float* cq   = (float*)(ws + 109051904);   // [16384]
  float* ck   = (float*)(ws + 109117440);   // [16384]
  float* invl = (float*)(ws + 109182976);   // [16384]
  float* wqbk = (float*)(ws + 109248512);   // [1024]
  float* wkbq = (float*)(ws + 109252608);   // [1024]
  float* c0   = (float*)(ws + 109256704);   // [1]
  f16_t* Ctx  = Xb;
  f16_t* probs = (f16_t*)d_out;             // [8][2048][2048] f16 == 64 MiB

  const size_t SH = 2048u * 1024u;
  const size_t SS = 2048u * 2048u;
  const size_t HS = 1024u * 2048u;

  // 1. prep: fused cast+transpose of X, W casts, bias vectors
  xprep_kernel<<<dim3(32, 64, 8), dim3(32, 8), 0, stream>>>(X, Xb, Xt);
  cast_f16_kernel<<<1024, 256, 0, stream>>>(Wq, Wqf);
  cast_f16_kernel<<<1024, 256, 0, stream>>>(Wk, Wkf);
  wvec_kernel<<<2049, 256, 0, stream>>>(Wq, bq, Wk, bk, wqbk, wkbq, c0);
  cqck_kernel<<<16384, 256, 0, stream>>>(X, wqbk, wkbq, cq, ck);

  // 2. Wkq = Wk · Wq^T   (tiny 1024^3, old 128^2 kernel)
  gemm_bt_kernel<<<dim3(8, 8, 1), 256, 0, stream>>>(
      Wkf, Wqf, Wkq, 1024, 1024, 1024, 1024);

  // 3. T = Xb · Wkq^T   (M=16384, N=1024, K=1024) -- 1D grid 256 (= 64x4x1)
  gemm256_kernel<<<256, 512, 0, stream>>>(
      Xb, Wkq, T, nullptr,
      1024, 1024, 1024, 1024, 0, 0, 0, 0, 64, 4);

  // 4. p = exp((T·X^T + bias)/32) masked + row-sum partials -- BK=32 variant,
  //    512 blocks (=8x8x8) -> 2 blocks/CU co-residency
  gemm256b32_kernel<<<512, 512, 0, stream>>>(
      T, Xb, probs, cq, ck, c0, masks, lpart,
      1024, 1024, 2048, 1024, 0.03125f, SH, SH, SS, 8, 8);

  // 5. invl = 1/rowsum
  lreduce_kernel<<<64, 256, 0, stream>>>(lpart, invl);

  // 6. context = (p/l) @ X   (per batch M=2048,N=1024,K=2048) -- 256 (=8x4x8)
  gemm256_kernel<<<256, 512, 0, stream>>>(
      probs, Xt, Ctx, invl,
      2048, 2048, 1024, 2048, 2, SS, HS, SH, 8, 4);

  // 7. out = LayerNorm(X + context)
  ln_kernel<<<16384, 256, 0, stream>>>(X, Ctx, gamma, beta, out);
}

// Round 9
// 415.267 us; speedup vs baseline: 1.0333x; 1.0259x over previous
//
#include <hip/hip_runtime.h>
#include <stdint.h>
#include <stddef.h>

// ---------- types ----------
typedef _Float16 f16_t;
typedef _Float16 f16x8 __attribute__((ext_vector_type(8)));
typedef _Float16 f16x4 __attribute__((ext_vector_type(4)));
typedef float    f32x4 __attribute__((ext_vector_type(4)));

#define AS_G __attribute__((address_space(1)))
#define AS_L __attribute__((address_space(3)))

__device__ __forceinline__ void gload_lds16(const void* g, void* l) {
  // async global->LDS, 16B per lane; HW writes lds_base + lane*16
  __builtin_amdgcn_global_load_lds((const AS_G uint32_t*)g, (AS_L uint32_t*)l, 16, 0, 0);
}

// stage 32 rows x 64 f16 (4 calls of 8 rows) for one wave
__device__ __forceinline__ void stage8(const f16_t* g, int ld, char* l) {
#pragma unroll
  for (int j = 0; j < 4; ++j)
    gload_lds16(g + (size_t)(j * 8) * ld, l + j * 1024);
}

#define LN_EPS 1e-12f

// ---------- fused X prep: Xb = f16(X) row-major, Xt = f16(X)^T per batch ----------
__global__ __launch_bounds__(256) void xprep_kernel(const float* __restrict__ in,
                                                    f16_t* __restrict__ xb,
                                                    f16_t* __restrict__ xt) {
  __shared__ float tile[32][33];
  int b = blockIdx.z;
  const float* inb = in + (size_t)b * 2048 * 1024;
  f16_t* xbb = xb + (size_t)b * 2048 * 1024;
  f16_t* xtb = xt + (size_t)b * 1024 * 2048;
  int tx = threadIdx.x, ty = threadIdx.y;  // 32 x 8
  int c0 = blockIdx.x * 32, r0 = blockIdx.y * 32;
#pragma unroll
  for (int i = 0; i < 32; i += 8) {
    float v = inb[(size_t)(r0 + ty + i) * 1024 + (c0 + tx)];
    tile[ty + i][tx] = v;
    xbb[(size_t)(r0 + ty + i) * 1024 + (c0 + tx)] = (f16_t)v;
  }
  __syncthreads();
#pragma unroll
  for (int i = 0; i < 32; i += 8)
    xtb[(size_t)(c0 + ty + i) * 2048 + (r0 + tx)] = (f16_t)tile[tx][ty + i];
}

// ---------- fused W cast + bias-prep (R9: one pass over Wq/Wk) ----------
// bid < 1024:   Wqf[row]=f16(Wq[row]), wqbk[row]=Wq[row]·bk
// bid < 2048:   Wkf[row]=f16(Wk[row]), wkbq[row]=Wk[row]·bq
// bid == 2048:  c0 = bq·bk
__global__ __launch_bounds__(256) void castwvec_kernel(const float* __restrict__ Wq,
                                                       const float* __restrict__ bq,
                                                       const float* __restrict__ Wk,
                                                       const float* __restrict__ bk,
                                                       f16_t* __restrict__ Wqf,
                                                       f16_t* __restrict__ Wkf,
                                                       float* __restrict__ wqbk,
                                                       float* __restrict__ wkbq,
                                                       float* __restrict__ c0) {
  __shared__ float red[4];
  int bid = blockIdx.x, tid = threadIdx.x;
  const float* rowp; const float* vecp; f16_t* outw; float* outd;
  if (bid < 1024)      { rowp = Wq + (size_t)bid * 1024; vecp = bk;
                         outw = Wqf + (size_t)bid * 1024; outd = wqbk + bid; }
  else if (bid < 2048) { rowp = Wk + (size_t)(bid - 1024) * 1024; vecp = bq;
                         outw = Wkf + (size_t)(bid - 1024) * 1024; outd = wkbq + (bid - 1024); }
  else                 { rowp = bq; vecp = bk; outw = nullptr; outd = c0; }
  float4 a = ((const float4*)rowp)[tid];
  float4 b = ((const float4*)vecp)[tid];
  if (outw) {
    f16x4 o = {(f16_t)a.x, (f16_t)a.y, (f16_t)a.z, (f16_t)a.w};
    ((f16x4*)outw)[tid] = o;
  }
  float s = a.x * b.x + a.y * b.y + a.z * b.z + a.w * b.w;
#pragma unroll
  for (int off = 32; off > 0; off >>= 1) s += __shfl_xor(s, off, 64);
  if ((tid & 63) == 0) red[tid >> 6] = s;
  __syncthreads();
  if (tid == 0) *outd = red[0] + red[1] + red[2] + red[3];
}

// ---------- cq[m]=Xb[m]·wqbk, ck[m]=Xb[m]·wkbq (R9: f16 X, half traffic) ----------
__global__ __launch_bounds__(256) void cqck_kernel(const f16_t* __restrict__ Xb,
                                                   const float* __restrict__ wqbk,
                                                   const float* __restrict__ wkbq,
                                                   float* __restrict__ cq,
                                                   float* __restrict__ ck) {
  __shared__ float r1[4], r2[4];
  int m = blockIdx.x, tid = threadIdx.x;
  f16x4 x = ((const f16x4*)(Xb + (size_t)m * 1024))[tid];
  float4 a = ((const float4*)wqbk)[tid];
  float4 b = ((const float4*)wkbq)[tid];
  float x0 = (float)x[0], x1 = (float)x[1], x2 = (float)x[2], x3 = (float)x[3];
  float s1 = x0 * a.x + x1 * a.y + x2 * a.z + x3 * a.w;
  float s2 = x0 * b.x + x1 * b.y + x2 * b.z + x3 * b.w;
#pragma unroll
  for (int off = 32; off > 0; off >>= 1) { s1 += __shfl_xor(s1, off, 64); s2 += __shfl_xor(s2, off, 64); }
  if ((tid & 63) == 0) { r1[tid >> 6] = s1; r2[tid >> 6] = s2; }
  __syncthreads();
  if (tid == 0) {
    cq[m] = r1[0] + r1[1] + r1[2] + r1[3];
    ck[m] = r2[0] + r2[1] + r2[2] + r2[3];
  }
}

// ---------- 128x128 MFMA GEMM (R1 structure) -- used only for the tiny 1024^3 Wkq GEMM ----------
__global__ __launch_bounds__(256) void gemm_bt_kernel(
    const f16_t* __restrict__ A, const f16_t* __restrict__ Bt, f16_t* __restrict__ C,
    int lda, int ldb, int ldc, int K) {
  __shared__ f16_t As[2][128 * 64];
  __shared__ f16_t Bs[2][128 * 64];

  const int tid = threadIdx.x;
  const int lane = tid & 63;
  const int wv = tid >> 6;
  const int m16 = lane & 15;
  const int quad = lane >> 4;
  const int wr = (wv >> 1) * 64;
  const int wc = (wv & 1) * 64;

  const f16_t* Ab = A + (size_t)blockIdx.x * 128 * lda;
  const f16_t* Bb = Bt + (size_t)blockIdx.y * 128 * ldb;

  const int lr8 = lane >> 3;
  const int ch8 = (lane & 7) ^ lr8;
  const f16_t* gA[4]; const f16_t* gB[4];
  f16_t* lA[4]; f16_t* lB[4];
#pragma unroll
  for (int j = 0; j < 4; ++j) {
    int row = wv * 32 + j * 8 + lr8;
    gA[j] = Ab + (size_t)row * lda + ch8 * 8;
    gB[j] = Bb + (size_t)row * ldb + ch8 * 8;
    lA[j] = &As[0][(wv * 32 + j * 8) * 64];
    lB[j] = &Bs[0][(wv * 32 + j * 8) * 64];
  }

  int aoff[4], boff[4], swz[2];
#pragma unroll
  for (int t = 0; t < 4; ++t) {
    aoff[t] = (wr + t * 16 + m16) * 64;
    boff[t] = (wc + t * 16 + m16) * 64;
  }
#pragma unroll
  for (int s = 0; s < 2; ++s)
    swz[s] = (((s << 2) | quad) ^ (m16 & 7)) * 8;

  f32x4 acc[4][4] = {};

#define STAGE(BUF, KOFF)                                       \
  _Pragma("unroll")                                            \
  for (int j = 0; j < 4; ++j) {                                \
    gload_lds16(gA[j] + (KOFF), lA[j] + (BUF) * (128 * 64));   \
    gload_lds16(gB[j] + (KOFF), lB[j] + (BUF) * (128 * 64));   \
  }

#define COMPUTE(BUF)                                                           \
  _Pragma("unroll")                                                            \
  for (int s = 0; s < 2; ++s) {                                                \
    f16x8 af[4], bfr[4];                                                       \
    _Pragma("unroll")                                                          \
    for (int t = 0; t < 4; ++t) {                                              \
      af[t]  = *(const f16x8*)&As[BUF][aoff[t] + swz[s]];                      \
      bfr[t] = *(const f16x8*)&Bs[BUF][boff[t] + swz[s]];                      \
    }                                                                          \
    _Pragma("unroll")                                                          \
    for (int rt = 0; rt < 4; ++rt)                                             \
      _Pragma("unroll")                                                        \
      for (int ct = 0; ct < 4; ++ct)                                           \
        acc[rt][ct] = __builtin_amdgcn_mfma_f32_16x16x32_f16(af[rt], bfr[ct],  \
                                                             acc[rt][ct], 0, 0, 0); \
  }

  STAGE(0, 0);
  __syncthreads();
  for (int k0 = 0; k0 < K; k0 += 128) {
    STAGE(1, k0 + 64);
    COMPUTE(0);
    __syncthreads();
    if (k0 + 128 < K) STAGE(0, k0 + 128);
    COMPUTE(1);
    __syncthreads();
  }
#undef STAGE
#undef COMPUTE

  const int row0 = blockIdx.x * 128 + wr + quad * 4;
  const int col0 = blockIdx.y * 128 + wc + m16;
#pragma unroll
  for (int ct = 0; ct < 4; ++ct)
#pragma unroll
    for (int rt = 0; rt < 4; ++rt)
#pragma unroll
      for (int r = 0; r < 4; ++r)
        C[(size_t)(row0 + rt * 16 + r) * ldc + col0 + ct * 16] = (f16_t)acc[rt][ct][r];
}

// ---------- 256x256 MFMA GEMM, BK=64 (R7-verified, all 3 modes) ----------
// Double-buffered 2-phase, one __syncthreads per 64-K step, XOR swizzle
// (chunk c of row r at slot c^(r&7), 0 bank conflicts measured), T1 XCD
// swizzle (FETCH 163->58MB verified), mr-outer epilogues (WRITE at floor).
// 512 threads = 8 waves (2M x 4N); per-wave out 128x64 = acc[8][4].
// Requires K % 128 == 0, M,N multiples of 256, grid % 8 == 0.
// mode 0: plain f16 store; mode 1: masked exp + row-sum partials; mode 2: *invl
// R8 lesson: BK=32 / 64KB LDS did NOT yield 2 blocks/CU (occupancy stayed 21%)
// and regressed 111->116us -- occupancy-family levers exhausted; this kernel
// sits at the 256^2+2-phase structural ceiling (~620 TF, m230-class).
__global__ __launch_bounds__(512) void gemm256_kernel(
    const f16_t* __restrict__ A, const f16_t* __restrict__ Bt, f16_t* __restrict__ C,
    const float* __restrict__ cq, const float* __restrict__ ck, const float* __restrict__ c0p,
    const int* __restrict__ mask, const float* __restrict__ invl, float* __restrict__ lpart,
    int lda, int ldb, int ldc, int K, float scale, int mode,
    size_t sA, size_t sB, size_t sC, int gx, int gy) {
  __shared__ f16_t As[2][256 * 64];   // 64 KB
  __shared__ f16_t Bs[2][256 * 64];   // 64 KB

  // ---- XCD-aware block remap (T1, bijective since nwg % 8 == 0) ----
  const int nwg = gridDim.x;
  const int lin = blockIdx.x;
  const int swzid = (lin & 7) * (nwg >> 3) + (lin >> 3);
  const int bx = swzid % gx;
  const int rem = swzid / gx;
  const int by = rem % gy;
  const int bz = rem / gy;

  const int tid = threadIdx.x;
  const int lane = tid & 63;
  const int wid = tid >> 6;        // 0..7
  const int wm = wid >> 2;         // 0..1  (row half)
  const int wn = wid & 3;          // 0..3  (col quarter)
  const int m16 = lane & 15;
  const int quad = lane >> 4;

  const f16_t* Ab = A + bz * sA + (size_t)bx * 256 * lda;
  const f16_t* Bb = Bt + bz * sB + (size_t)by * 256 * ldb;

  const int lr8 = lane >> 3;
  const int ch8 = (lane & 7) ^ lr8;
  const f16_t* gA = Ab + (size_t)(wid * 32 + lr8) * lda + ch8 * 8;
  const f16_t* gB = Bb + (size_t)(wid * 32 + lr8) * ldb + ch8 * 8;
  char* ldsA = (char*)As + wid * 4096;   // + buf*32768
  char* ldsB = (char*)Bs + wid * 4096;

  int aoff[8], boff[4], swz[2];
#pragma unroll
  for (int mr = 0; mr < 8; ++mr) aoff[mr] = (wm * 128 + mr * 16 + m16) * 64;
#pragma unroll
  for (int nr = 0; nr < 4; ++nr) boff[nr] = (wn * 64 + nr * 16 + m16) * 64;
#pragma unroll
  for (int s = 0; s < 2; ++s)
    swz[s] = (((s << 2) | quad) ^ (m16 & 7)) * 8;

  f32x4 acc[8][4] = {};

#define STAGE(BUF, KOFF)                                 \
  stage8(gA + (KOFF), lda, ldsA + (BUF) * 32768);        \
  stage8(gB + (KOFF), ldb, ldsB + (BUF) * 32768);

#define COMPUTE(BUF)                                                           \
  _Pragma("unroll")                                                            \
  for (int s = 0; s < 2; ++s) {                                                \
    f16x8 af[8], bf[4];                                                        \
    _Pragma("unroll")                                                          \
    for (int mr = 0; mr < 8; ++mr) af[mr] = *(const f16x8*)&As[BUF][aoff[mr] + swz[s]]; \
    _Pragma("unroll")                                                          \
    for (int nr = 0; nr < 4; ++nr) bf[nr] = *(const f16x8*)&Bs[BUF][boff[nr] + swz[s]]; \
    _Pragma("unroll")                                                          \
    for (int mr = 0; mr < 8; ++mr)                                             \
      _Pragma("unroll")                                                        \
      for (int nr = 0; nr < 4; ++nr)                                           \
        acc[mr][nr] = __builtin_amdgcn_mfma_f32_16x16x32_f16(af[mr], bf[nr],   \
                                                             acc[mr][nr], 0, 0, 0); \
  }

  STAGE(0, 0);
  __syncthreads();
  for (int k0 = 0; k0 < K; k0 += 128) {
    STAGE(1, k0 + 64);
    COMPUTE(0);
    __syncthreads();
    if (k0 + 128 < K) STAGE(0, k0 + 128);
    COMPUTE(1);
    __syncthreads();
  }
#undef STAGE
#undef COMPUTE

  // epilogue; C/D layout: col = lane&15, row = quad*4 + reg  [m89-verified]
  // mr-outer/nr-inner: 4 consecutive stores cover a row's 128B segment.
  f16_t* Cb = C + bz * sC;
  const int row0 = bx * 256 + wm * 128 + quad * 4;
  const int col0 = by * 256 + wn * 64 + m16;
  if (mode == 0) {
#pragma unroll
    for (int mr = 0; mr < 8; ++mr)
#pragma unroll
      for (int r = 0; r < 4; ++r) {
        f16_t* rowp = Cb + (size_t)(row0 + mr * 16 + r) * ldc + col0;
#pragma unroll
        for (int nr = 0; nr < 4; ++nr)
          rowp[nr * 16] = (f16_t)acc[mr][nr][r];
      }
  } else if (mode == 1) {
    const int* mp = mask + bz * 2048;
    const size_t rowg0 = bz * 2048 + row0;
    const float c0 = *c0p;
    float ckv[4]; bool keep[4];
#pragma unroll
    for (int nr = 0; nr < 4; ++nr) {
      int col = col0 + nr * 16;
      keep[nr] = (mp[col] != 0);
      ckv[nr] = ck[bz * 2048 + col];
    }
    float rsum[8][4];
#pragma unroll
    for (int mr = 0; mr < 8; ++mr)
#pragma unroll
      for (int r = 0; r < 4; ++r) {
        float cqv = cq[rowg0 + mr * 16 + r];
        f16_t* rowp = Cb + (size_t)(row0 + mr * 16 + r) * ldc + col0;
        float rs_ = 0.f;
#pragma unroll
        for (int nr = 0; nr < 4; ++nr) {
          float p = keep[nr] ? __expf((acc[mr][nr][r] + cqv + ckv[nr] + c0) * scale) : 0.f;
          rs_ += p;
          rowp[nr * 16] = (f16_t)p;
        }
        rsum[mr][r] = rs_;
      }
    const int chunk = by * 4 + wn;
#pragma unroll
    for (int mr = 0; mr < 8; ++mr)
#pragma unroll
      for (int r = 0; r < 4; ++r) {
        float v = rsum[mr][r];
        v += __shfl_xor(v, 1, 16);
        v += __shfl_xor(v, 2, 16);
        v += __shfl_xor(v, 4, 16);
        v += __shfl_xor(v, 8, 16);
        if (m16 == 0) lpart[(rowg0 + mr * 16 + r) * 32 + chunk] = v;
      }
  } else {
    const size_t rowg0 = bz * 2048 + row0;
#pragma unroll
    for (int mr = 0; mr < 8; ++mr)
#pragma unroll
      for (int r = 0; r < 4; ++r) {
        float il = invl[rowg0 + mr * 16 + r];
        f16_t* rowp = Cb + (size_t)(row0 + mr * 16 + r) * ldc + col0;
#pragma unroll
        for (int nr = 0; nr < 4; ++nr)
          rowp[nr * 16] = (f16_t)(acc[mr][nr][r] * il);
      }
  }
}

// ---------- l reduce: invl[m] = 1 / sum(lpart[m][0..32)) ----------
__global__ __launch_bounds__(256) void lreduce_kernel(const float* __restrict__ lpart,
                                                      float* __restrict__ invl) {
  int m = blockIdx.x * 256 + threadIdx.x;
  const float4* p = (const float4*)(lpart + (size_t)m * 32);
  float s = 0.f;
#pragma unroll
  for (int j = 0; j < 8; ++j) {
    float4 v = p[j];
    s += v.x + v.y + v.z + v.w;
  }
  invl[m] = 1.0f / fmaxf(s, 1e-30f);
}

// ---------- residual + LayerNorm: out[row] = LN(X[row] + Ctx[row]) ----------
__global__ __launch_bounds__(256) void ln_kernel(const float* __restrict__ X,
                                                 const f16_t* __restrict__ Ctx,
                                                 const float* __restrict__ gamma,
                                                 const float* __restrict__ beta,
                                                 float* __restrict__ out) {
  __shared__ float r1[4], r2[4];
  const int tid = threadIdx.x;
  const size_t base = (size_t)blockIdx.x * 1024;
  float4 xv = ((const float4*)(X + base))[tid];
  f16x4 cv = ((const f16x4*)(Ctx + base))[tid];
  float v0 = xv.x + (float)cv[0];
  float v1 = xv.y + (float)cv[1];
  float v2 = xv.z + (float)cv[2];
  float v3 = xv.w + (float)cv[3];
  float s1 = v0 + v1 + v2 + v3;
  float s2 = v0 * v0 + v1 * v1 + v2 * v2 + v3 * v3;
#pragma unroll
  for (int off = 32; off > 0; off >>= 1) {
    s1 += __shfl_xor(s1, off, 64);
    s2 += __shfl_xor(s2, off, 64);
  }
  if ((tid & 63) == 0) { r1[tid >> 6] = s1; r2[tid >> 6] = s2; }
  __syncthreads();
  s1 = r1[0] + r1[1] + r1[2] + r1[3];
  s2 = r2[0] + r2[1] + r2[2] + r2[3];
  float mu = s1 * (1.0f / 1024.0f);
  float var = s2 * (1.0f / 1024.0f) - mu * mu;
  float rs = rsqrtf(fmaxf(var, 0.0f) + LN_EPS);
  float4 gv = ((const float4*)gamma)[tid];
  float4 bv = ((const float4*)beta)[tid];
  float4 o;
  o.x = (v0 - mu) * rs * gv.x + bv.x;
  o.y = (v1 - mu) * rs * gv.y + bv.y;
  o.z = (v2 - mu) * rs * gv.z + bv.z;
  o.w = (v3 - mu) * rs * gv.w + bv.w;
  ((float4*)(out + base))[tid] = o;
}

// ---------- launch ----------
extern "C" void kernel_launch(void* const* d_in, const int* in_sizes, int n_in,
                              void* d_out, int out_size, void* d_ws, size_t ws_size,
                              hipStream_t stream) {
  const float* X     = (const float*)d_in[0];  // [8,2048,1024]
  const int*   masks = (const int*)d_in[1];    // [8,2048]
  const float* Wq    = (const float*)d_in[2];  // [1024,1024]
  const float* bq    = (const float*)d_in[3];
  const float* Wk    = (const float*)d_in[4];
  const float* bk    = (const float*)d_in[5];
  const float* gamma = (const float*)d_in[6];
  const float* beta  = (const float*)d_in[7];
  float* out = (float*)d_out;

  if (ws_size < 115343360u) return;  // need ~110 MiB
  char* ws = (char*)d_ws;
  f16_t* Xb   = (f16_t*)(ws + 0);           // [16384][1024] f16 (later Ctx)
  f16_t* Xt   = (f16_t*)(ws + 33554432);    // [8][1024][2048] f16
  f16_t* T    = (f16_t*)(ws + 67108864);    // [16384][1024] f16
  f16_t* Wqf  = (f16_t*)(ws + 100663296);   // [1024][1024] f16
  f16_t* Wkf  = (f16_t*)(ws + 102760448);   // [1024][1024] f16
  f16_t* Wkq  = (f16_t*)(ws + 104857600);   // [1024][1024] f16 (Wk·Wq^T)
  float* lpart= (float*)(ws + 106954752);   // [16384][32] f32
  float* cq   = (float*)(ws + 109051904);   // [16384]
  float* ck   = (float*)(ws + 109117440);   // [16384]
  float* invl = (float*)(ws + 109182976);   // [16384]
  float* wqbk = (float*)(ws + 109248512);   // [1024]
  float* wkbq = (float*)(ws + 109252608);   // [1024]
  float* c0   = (float*)(ws + 109256704);   // [1]
  f16_t* Ctx  = Xb;
  f16_t* probs = (f16_t*)d_out;             // [8][2048][2048] f16 == 64 MiB

  const size_t SH = 2048u * 1024u;
  const size_t SS = 2048u * 2048u;
  const size_t HS = 1024u * 2048u;

  // 1. prep: fused cast+transpose of X; fused W cast + bias vectors;
  //    cqck from f16 Xb (half traffic)
  xprep_kernel<<<dim3(32, 64, 8), dim3(32, 8), 0, stream>>>(X, Xb, Xt);
  castwvec_kernel<<<2049, 256, 0, stream>>>(Wq, bq, Wk, bk, Wqf, Wkf, wqbk, wkbq, c0);
  cqck_kernel<<<16384, 256, 0, stream>>>(Xb, wqbk, wkbq, cq, ck);

  // 2. Wkq = Wk · Wq^T   (tiny 1024^3, old 128^2 kernel)
  gemm_bt_kernel<<<dim3(8, 8, 1), 256, 0, stream>>>(
      Wkf, Wqf, Wkq, 1024, 1024, 1024, 1024);

  // 3. T = Xb · Wkq^T   (M=16384, N=1024, K=1024) -- 1D grid 256 (= 64x4x1)
  gemm256_kernel<<<256, 512, 0, stream>>>(
      Xb, Wkq, T, nullptr, nullptr, nullptr, nullptr, nullptr, nullptr,
      1024, 1024, 1024, 1024, 0.f, 0, 0, 0, 0, 64, 4);

  // 4. p = exp((T·X^T + bias-terms)/32) masked + row-sum partials -- 512 (=8x8x8)
  gemm256_kernel<<<512, 512, 0, stream>>>(
      T, Xb, probs, cq, ck, c0, masks, nullptr, lpart,
      1024, 1024, 2048, 1024, 0.03125f, 1, SH, SH, SS, 8, 8);

  // 5. invl = 1/rowsum
  lreduce_kernel<<<64, 256, 0, stream>>>(lpart, invl);

  // 6. context = (p/l) @ X   (per batch M=2048,N=1024,K=2048) -- 256 (=8x4x8)
  gemm256_kernel<<<256, 512, 0, stream>>>(
      probs, Xt, Ctx, nullptr, nullptr, nullptr, nullptr, invl, nullptr,
      2048, 2048, 1024, 2048, 0.f, 2, SS, HS, SH, 8, 4);

  // 7. out = LayerNorm(X + context)
  ln_kernel<<<16384, 256, 0, stream>>>(X, Ctx, gamma, beta, out);
}